// Round 11
// baseline (492.668 us; speedup 1.0000x reference)
//
#include <hip/hip_runtime.h>

#define T_     24
#define LAMDA_ 0.2f

// output layout (flat f32): outs[24,64,256] | cs[64,256] | las[24,64,32] | gas[24,64,256]
#define OFF_CS  393216
#define OFF_LAS 409600
#define OFF_GAS 458752

__device__ __forceinline__ float clamp15(float x){ return fminf(15.f, fmaxf(-15.f, x)); }
__device__ __forceinline__ float rcp_(float x){ return __builtin_amdgcn_rcpf(x); }

typedef float v2f __attribute__((ext_vector_type(2)));
typedef float v4f __attribute__((ext_vector_type(4)));
#define PKFMA(a,b,c) __builtin_elementwise_fma((a),(b),(c))

// ---------------------------------------------------------------------------
// R20: R19 neutral -> t-loop is barrier/latency-bound. This round removes a
// whole barrier: phase E is REPLICATED PER WAVE (its inputs are wave-agnostic
// after barrier #3; its xv output is deterministic). Every wave computes the
// full gas softmax (4 s/lane) + sl softmax (lanes<32) and writes the COMPLETE
// 288-entry xv itself, then falls straight into A(t+1) -- a wave's own LDS
// writes are ordered before its own reads, and other waves' duplicate writes
// carry identical values (benign). E(t+1) can't clobber early: it sits behind
// barriers #1-#3 of t+1. Outputs (lasb/gasb) written by wave 0 only; final
// __syncthreads() before the flush replaces barrier #4's visibility role.
// li/gi prefetch widened to all lanes, issued after barrier #2 (D hides it).
// R19's neutral C-weight-in-A hoist reverted (frees 16 transient regs).
// Barriers/step: 4 -> 3. Tripwire: WRITE_SIZE ~3.3MB; >10MB = spill.
// If this lands <3%: declare the serial-recurrence floor.
// ---------------------------------------------------------------------------
__global__ __launch_bounds__(1024, 4) void spat_kernel(
    const float* __restrict__ li,  const float* __restrict__ gi,
    const float* __restrict__ ls,  const float* __restrict__ gs,
    const float* __restrict__ dist,
    const float* __restrict__ la0, const float* __restrict__ ga0,
    const float* __restrict__ Wcl, const float* __restrict__ bcl,
    const float* __restrict__ Wll, const float* __restrict__ bll, const float* __restrict__ vl,
    const float* __restrict__ Wcg, const float* __restrict__ bcg,
    const float* __restrict__ Wlg, const float* __restrict__ blg, const float* __restrict__ vg,
    const float* __restrict__ Wih, const float* __restrict__ bih, const float* __restrict__ bhh,
    float* __restrict__ out)
{
    __shared__ float El[800];                // exp(2*hf_l), idx l*25+o
    __shared__ float outb[6144];             // h outputs  [t][i]
    __shared__ float gasb[6144];             // gas        [t][s]
    __shared__ float lasb[768];              // las        [t][l]
    __shared__ float csb[256];               // c at t=23
    __shared__ float slred[800];             // s_l partials, idx l*25+o
    __shared__ __align__(16) union {
        float wcg[6144];                     // Wcg staging (init only)
        struct {
            float sgred[1024];
            float xv[288];
            float cq[256];
        } p;
    } U;
    __shared__ float dstf[256];
    __shared__ float bsum[768];              // bih+bhh: [u]=i, [256+u]=g, [512+u]=o
    __shared__ float bcf[48];                // bll|blg
    __shared__ __align__(16) float4 pl4[12], pg4[12];  // pair coeffs (A0,A1,B1,B2)
    __shared__ float vlf[24], vgf[24], cbuf[2];

    const int b = blockIdx.x, tid = threadIdx.x;
    const int s = tid & 255, ogrp = tid >> 8;
    const int lane = tid & 63, wid = tid >> 6;

    // ---- small init (before first barrier) ----
    if (tid < 256) dstf[tid] = dist[b*256 + tid];
    if (tid < 24)  { vlf[tid] = vl[tid]; vgf[tid] = vg[tid]; }
    if (tid < 48)  bcf[tid] = (tid < 24) ? bll[tid] : blg[tid - 24];
    if (tid < 768) {
        const int wrow = tid + ((tid >= 256) ? 256 : 0);
        bsum[tid] = bih[wrow] + bhh[wrow];
    }
    if (tid == 0)  { float s1 = 0.f; for (int d = 0; d < 24; d++) s1 += vl[d]; cbuf[0] = s1; }
    if (tid == 1)  { float s1 = 0.f; for (int d = 0; d < 24; d++) s1 += vg[d]; cbuf[1] = s1; }

    // ---- hf_g: thread (s, ogrp) accumulates 6 o's over c<24, j<32 (packed) ----
    v2f acc2[6];
#pragma unroll
    for (int i = 0; i < 6; i++) acc2[i] = (v2f){bcg[ogrp*6 + i], 0.f};

#pragma unroll 1
    for (int hc = 0; hc < 3; hc++) {
        for (int k = tid; k < 6144; k += 1024) {
            const int o = k >> 8, r = k & 255;
            U.wcg[k] = Wcg[o*768 + hc*256 + r];
        }
        __syncthreads();
#pragma unroll 1
        for (int cc = 0; cc < 8; cc++) {
            const int c = hc*8 + cc;
            const v4f* gp = (const v4f*)(gs + ((size_t)b*196608 + c*8192 + s*32));
#pragma unroll
            for (int h = 0; h < 2; h++) {            // two 16-float halves of j
                const v4f g0 = gp[h*4 + 0], g1 = gp[h*4 + 1];
                const v4f g2 = gp[h*4 + 2], g3 = gp[h*4 + 3];
#pragma unroll
                for (int i = 0; i < 6; i++) {
                    const v4f* wp = (const v4f*)(U.wcg + ((ogrp*6 + i)*256 + cc*32)) + h*4;
                    const v4f w0 = wp[0], w1 = wp[1], w2 = wp[2], w3 = wp[3];
                    v2f a = acc2[i];
                    a = PKFMA(w0.xy, g0.xy, a); a = PKFMA(w0.zw, g0.zw, a);
                    a = PKFMA(w1.xy, g1.xy, a); a = PKFMA(w1.zw, g1.zw, a);
                    a = PKFMA(w2.xy, g2.xy, a); a = PKFMA(w2.zw, g2.zw, a);
                    a = PKFMA(w3.xy, g3.xy, a); a = PKFMA(w3.zw, g3.zw, a);
                    acc2[i] = a;
                }
            }
        }
        __syncthreads();
    }
    // z-values for phase D, held in registers for the whole t-loop.
    float Ewr[6];
#pragma unroll
    for (int i = 0; i < 6; i++)
        Ewr[i] = __expf(2.f*clamp15(acc2[i].x + acc2[i].y));

    // ---- hf_l -> El (transposed: l*25+o) ----
    if (tid < 768) {
        const int o = tid >> 5, l = tid & 31;
        float a = bcl[o];
        for (int c = 0; c < 24; c++)
            a = fmaf(Wcl[o*24 + c], ls[b*768 + c*32 + l], a);
        El[l*25 + o] = __expf(2.f*clamp15(a));
    }

    // ---- x for t=0 (wcg union dead after hc-loop barrier) ----
    if (tid < 288) {
        if (tid < 32) U.p.xv[tid] = la0[b*32 + tid] * li[b*32 + tid];
        else { const int ss = tid - 32; U.p.xv[tid] = ga0[b*256 + ss] * gi[b*256 + ss]; }
    }
    __syncthreads();

    const int u8 = tid & 7, slot = tid >> 3;   // A team layout (128 slots)
    const int u0 = slot*2;                     // slot owns units u0, u0+1

    // s_l per-thread geometry + El register hoist (constant over t)
    const int l24 = tid / 24, o24 = tid - l24*24;   // valid for tid<768
    const float Elr = (tid < 768) ? El[l24*25 + o24] : 0.f;
    const float El2r = Elr * Elr;

#pragma unroll 1
    for (int t = 0; t < T_; t++) {
        // ---- A: gates GEMV (i/g/o rows of 2 units per slot), packed,
        //      fused LSTM tail ----
        {
            const v4f* xp = (const v4f*)U.p.xv;
            v2f br0 = {0.f,0.f}, br1 = {0.f,0.f}, br2 = {0.f,0.f};
            v2f br3 = {0.f,0.f}, br4 = {0.f,0.f}, br5 = {0.f,0.f};
#pragma unroll 1
            for (int jc = 0; jc < 3; jc++) {
                const v4f x0 = xp[jc*24 + u8];
                const v4f x1 = xp[jc*24 + 8 + u8];
                const v4f x2 = xp[jc*24 + 16 + u8];

#define KROW(WROW, AR) { \
                const v4f* wp_ = (const v4f*)(Wih + (size_t)(WROW)*288) + jc*24 + u8; \
                const v4f w0_ = wp_[0], w1_ = wp_[8], w2_ = wp_[16]; \
                v2f a_ = AR; \
                a_ = PKFMA(w0_.xy, x0.xy, a_); a_ = PKFMA(w0_.zw, x0.zw, a_); \
                a_ = PKFMA(w1_.xy, x1.xy, a_); a_ = PKFMA(w1_.zw, x1.zw, a_); \
                a_ = PKFMA(w2_.xy, x2.xy, a_); a_ = PKFMA(w2_.zw, x2.zw, a_); \
                AR = a_; }

                KROW(u0,       br0) KROW(512 + u0, br1) KROW(768 + u0, br2)
                __builtin_amdgcn_sched_barrier(0);
                KROW(u0 + 1,   br3) KROW(513 + u0, br4) KROW(769 + u0, br5)
                __builtin_amdgcn_sched_barrier(0);
#undef KROW
            }
            float ar0 = br0.x + br0.y, ar1 = br1.x + br1.y, ar2 = br2.x + br2.y;
            float ar3 = br3.x + br3.y, ar4 = br4.x + br4.y, ar5 = br5.x + br5.y;
            ar0 += __shfl_xor(ar0, 1); ar0 += __shfl_xor(ar0, 2); ar0 += __shfl_xor(ar0, 4);
            ar1 += __shfl_xor(ar1, 1); ar1 += __shfl_xor(ar1, 2); ar1 += __shfl_xor(ar1, 4);
            ar2 += __shfl_xor(ar2, 1); ar2 += __shfl_xor(ar2, 2); ar2 += __shfl_xor(ar2, 4);
            ar3 += __shfl_xor(ar3, 1); ar3 += __shfl_xor(ar3, 2); ar3 += __shfl_xor(ar3, 4);
            ar4 += __shfl_xor(ar4, 1); ar4 += __shfl_xor(ar4, 2); ar4 += __shfl_xor(ar4, 4);
            ar5 += __shfl_xor(ar5, 1); ar5 += __shfl_xor(ar5, 2); ar5 += __shfl_xor(ar5, 4);
            if (u8 < 2) {                     // lane0 -> cell u0, lane1 -> cell u0+1
                const int uu = u0 + u8;
                const float ig = (u8 ? ar3 : ar0) + bsum[uu];
                const float gg = (u8 ? ar4 : ar1) + bsum[256 + uu];
                const float ot = (u8 ? ar5 : ar2) + bsum[512 + uu];
                const float sig_i = rcp_(1.f + __expf(-ig));
                const float th_g  = 1.f - 2.f*rcp_(1.f + __expf(2.f*clamp15(gg)));
                const float c     = sig_i * th_g;
                const float sig_o = rcp_(1.f + __expf(-ot));
                const float th_c  = 1.f - 2.f*rcp_(1.f + __expf(2.f*c));
                const float h     = sig_o * th_c;
                U.p.cq[uu] = c;
                outb[t*256 + uu] = h;
                if (t == T_ - 1) csb[uu] = c;
            }
        }
        __syncthreads();                              // #1: cq/outb ready

        // ---- C: 48 dots x 16-lane teams (packed); F = exp(2y); pair coeffs ----
        if (tid < 768) {
            const int dot = tid >> 4, l16 = tid & 15;
            const float* Wr = (dot < 24) ? (Wll + dot*256) : (Wlg + (dot - 24)*256);
            const v4f* wp = (const v4f*)Wr + l16*4;
            const v4f* cp = (const v4f*)U.p.cq + l16*4;
            v2f a2 = {0.f, 0.f};
#pragma unroll
            for (int m = 0; m < 4; m++) {
                const v4f w0 = wp[m], c0 = cp[m];
                a2 = PKFMA(w0.xy, c0.xy, a2);
                a2 = PKFMA(w0.zw, c0.zw, a2);
            }
            float a = a2.x + a2.y;
            a += __shfl_xor(a, 1); a += __shfl_xor(a, 2);
            a += __shfl_xor(a, 4); a += __shfl_xor(a, 8);
            const float F  = __expf(2.f*clamp15(a + bcf[dot]));
            const float v  = (dot < 24) ? vlf[dot] : vgf[dot - 24];
            const float Fo = __shfl_xor(F, 16);        // partner team (dot^1)
            const float vo = (dot < 24) ? vlf[dot ^ 1] : vgf[(dot ^ 1) - 24];
            if ((tid & 31) == 0) {                     // lane 0 of even dot
                const float A0 = v + vo;
                const float A1 = fmaf(v, Fo, vo * F);
                const float B1 = F + Fo;
                const float B2 = F * Fo;
                const int P2 = dot >> 1;               // 0..23
                if (P2 < 12) pl4[P2]      = make_float4(A0, A1, B1, B2);
                else         pg4[P2 - 12] = make_float4(A0, A1, B1, B2);
            }
        }
        __syncthreads();                              // #2

        // prefetch next-step inputs for the replicated x-build (all lanes;
        // issued here so D hides the latency; 16x-replicated reads hit L2)
        float liN = 0.f, giN0 = 0.f, giN1 = 0.f, giN2 = 0.f, giN3 = 0.f;
        if (t < T_ - 1) {
            if (lane < 32) liN = li[(t+1)*2048 + b*32 + lane];
            giN0 = gi[(t+1)*16384 + b*256 + lane];
            giN1 = gi[(t+1)*16384 + b*256 + lane + 64];
            giN2 = gi[(t+1)*16384 + b*256 + lane + 128];
            giN3 = gi[(t+1)*16384 + b*256 + lane + 192];
        }

        // ---- D: s_g partials (all threads, packed, z in regs)
        //      + s_l partials (tid<768, E in reg) ----
        {
            const v2f zv0 = {Ewr[0], Ewr[1]}, zv1 = {Ewr[2], Ewr[3]}, zv2 = {Ewr[4], Ewr[5]};
            const v2f z2v0 = zv0*zv0, z2v1 = zv1*zv1, z2v2 = zv2*zv2;
            const v2f one2 = {1.f, 1.f};
            v2f acc2d = {0.f, 0.f};
#pragma unroll 4
            for (int p = 0; p < 12; p++) {
                const float4 q = pg4[p];
                const v2f qx = {q.x, q.x}, qy = {q.y, q.y};
                const v2f qz = {q.z, q.z}, qw = {q.w, q.w};
                const v2f n0 = PKFMA(zv0, qy, qx);
                const v2f n1 = PKFMA(zv1, qy, qx);
                const v2f n2 = PKFMA(zv2, qy, qx);
                const v2f d0 = PKFMA(z2v0, qw, PKFMA(zv0, qz, one2));
                const v2f d1 = PKFMA(z2v1, qw, PKFMA(zv1, qz, one2));
                const v2f d2 = PKFMA(z2v2, qw, PKFMA(zv2, qz, one2));
                const v2f r0 = {rcp_(d0.x), rcp_(d0.y)};
                const v2f r1 = {rcp_(d1.x), rcp_(d1.y)};
                const v2f r2 = {rcp_(d2.x), rcp_(d2.y)};
                acc2d = PKFMA(n0, r0, acc2d);
                acc2d = PKFMA(n1, r1, acc2d);
                acc2d = PKFMA(n2, r2, acc2d);
            }
            U.p.sgred[tid] = acc2d.x + acc2d.y;
        }
        if (tid < 768) {
            float b0 = 0.f, b1 = 0.f;
#pragma unroll 4
            for (int p = 0; p < 12; p += 2) {
                const float4 q0 = pl4[p], q1 = pl4[p+1];
                const float n0 = fmaf(Elr, q0.y, q0.x);
                const float d0 = fmaf(El2r, q0.w, fmaf(Elr, q0.z, 1.f));
                const float n1 = fmaf(Elr, q1.y, q1.x);
                const float d1 = fmaf(El2r, q1.w, fmaf(Elr, q1.z, 1.f));
                b0 = fmaf(n0, rcp_(d0), b0);
                b1 = fmaf(n1, rcp_(d1), b1);
            }
            slred[l24*25 + o24] = b0 + b1;
        }
        __syncthreads();                              // #3

        // ---- E (replicated per wave): both softmaxes + x-build; NO barrier
        //      after -- each wave writes the full xv itself and proceeds ----
        {
            // gas softmax: 4 s per lane (s = lane + 64k)
            const float t0 = U.p.sgred[lane]     + U.p.sgred[256+lane]     + U.p.sgred[512+lane]     + U.p.sgred[768+lane];
            const float t1 = U.p.sgred[lane+64]  + U.p.sgred[256+lane+64]  + U.p.sgred[512+lane+64]  + U.p.sgred[768+lane+64];
            const float t2 = U.p.sgred[lane+128] + U.p.sgred[256+lane+128] + U.p.sgred[512+lane+128] + U.p.sgred[768+lane+128];
            const float t3 = U.p.sgred[lane+192] + U.p.sgred[256+lane+192] + U.p.sgred[512+lane+192] + U.p.sgred[768+lane+192];
            const float vv0 = (1.f-LAMDA_)*(24.f*cbuf[1] - 2.f*t0) + LAMDA_*dstf[lane];
            const float vv1 = (1.f-LAMDA_)*(24.f*cbuf[1] - 2.f*t1) + LAMDA_*dstf[lane+64];
            const float vv2 = (1.f-LAMDA_)*(24.f*cbuf[1] - 2.f*t2) + LAMDA_*dstf[lane+128];
            const float vv3 = (1.f-LAMDA_)*(24.f*cbuf[1] - 2.f*t3) + LAMDA_*dstf[lane+192];
            float m = fmaxf(fmaxf(vv0, vv1), fmaxf(vv2, vv3));
#pragma unroll
            for (int mk = 32; mk >= 1; mk >>= 1) m = fmaxf(m, __shfl_xor(m, mk));
            const float e0 = __expf(vv0 - m), e1 = __expf(vv1 - m);
            const float e2 = __expf(vv2 - m), e3 = __expf(vv3 - m);
            float ss = (e0 + e1) + (e2 + e3);
#pragma unroll
            for (int mk = 32; mk >= 1; mk >>= 1) ss += __shfl_xor(ss, mk);
            const float inv = rcp_(ss);
            const float r0 = e0*inv, r1 = e1*inv, r2 = e2*inv, r3 = e3*inv;
            if (wid == 0) {
                float* gb = gasb + t*256;
                gb[lane] = r0; gb[lane+64] = r1; gb[lane+128] = r2; gb[lane+192] = r3;
            }
            if (t < T_ - 1) {
                U.p.xv[32+lane]     = r0 * giN0;
                U.p.xv[32+lane+64]  = r1 * giN1;
                U.p.xv[32+lane+128] = r2 * giN2;
                U.p.xv[32+lane+192] = r3 * giN3;
            }
            // sl softmax: lanes 0..31 (shfl_xor <=16 stays within the half)
            if (lane < 32) {
                float tot = 0.f;
#pragma unroll
                for (int o2 = 0; o2 < 24; o2++) tot += slred[lane*25 + o2];
                const float sv = 24.f*cbuf[0] - 2.f*tot;
                float ml = sv;
#pragma unroll
                for (int mk = 16; mk >= 1; mk >>= 1) ml = fmaxf(ml, __shfl_xor(ml, mk));
                const float e = __expf(sv - ml);
                float ssl = e;
#pragma unroll
                for (int mk = 16; mk >= 1; mk >>= 1) ssl += __shfl_xor(ssl, mk);
                const float r = e * rcp_(ssl);
                if (wid == 0) lasb[t*32 + lane] = r;
                if (t < T_ - 1) U.p.xv[lane] = r * liN;
            }
        }
        // no barrier: each wave wrote the complete xv itself; duplicate
        // writes from other waves carry identical values (benign).
    }
    __syncthreads();   // visibility of wave-0 output writes for the flush

    // ---- final flush: LDS output buffers -> global, coalesced ----
    for (int k = tid; k < 6144; k += 1024) {
        const int tt = k >> 8, ii = k & 255;
        out[tt*16384 + b*256 + ii]           = outb[k];
        out[OFF_GAS + tt*16384 + b*256 + ii] = gasb[k];
    }
    if (tid < 768) out[OFF_LAS + (tid >> 5)*2048 + b*32 + (tid & 31)] = lasb[tid];
    if (tid < 256) out[OFF_CS + b*256 + tid] = csb[tid];
}

extern "C" void kernel_launch(void* const* d_in, const int* in_sizes, int n_in,
                              void* d_out, int out_size, void* d_ws, size_t ws_size,
                              hipStream_t stream)
{
    const float* li   = (const float*)d_in[0];
    const float* gi   = (const float*)d_in[1];
    const float* ls   = (const float*)d_in[2];
    const float* gs   = (const float*)d_in[3];
    const float* dist = (const float*)d_in[4];
    const float* la0  = (const float*)d_in[5];
    const float* ga0  = (const float*)d_in[6];
    const float* Wcl  = (const float*)d_in[7];
    const float* bcl  = (const float*)d_in[8];
    const float* Wll  = (const float*)d_in[9];
    const float* bll  = (const float*)d_in[10];
    const float* vl   = (const float*)d_in[11];
    const float* Wcg  = (const float*)d_in[12];
    const float* bcg  = (const float*)d_in[13];
    const float* Wlg  = (const float*)d_in[14];
    const float* blg  = (const float*)d_in[15];
    const float* vg   = (const float*)d_in[16];
    const float* Wih  = (const float*)d_in[17];
    const float* bih  = (const float*)d_in[18];
    const float* bhh  = (const float*)d_in[19];

    spat_kernel<<<64, 1024, 0, stream>>>(li, gi, ls, gs, dist, la0, ga0,
                                         Wcl, bcl, Wll, bll, vl,
                                         Wcg, bcg, Wlg, blg, vg,
                                         Wih, bih, bhh, (float*)d_out);
}

// Round 12
// 478.198 us; speedup vs baseline: 1.0303x; 1.0303x over previous
//
#include <hip/hip_runtime.h>

#define T_     24
#define LAMDA_ 0.2f

// output layout (flat f32): outs[24,64,256] | cs[64,256] | las[24,64,32] | gas[24,64,256]
#define OFF_CS  393216
#define OFF_LAS 409600
#define OFF_GAS 458752

__device__ __forceinline__ float clamp15(float x){ return fminf(15.f, fmaxf(-15.f, x)); }
__device__ __forceinline__ float rcp_(float x){ return __builtin_amdgcn_rcpf(x); }

typedef float v2f __attribute__((ext_vector_type(2)));
typedef float v4f __attribute__((ext_vector_type(4)));
#define PKFMA(a,b,c) __builtin_elementwise_fma((a),(b),(c))

// ---------------------------------------------------------------------------
// R21 = exact revert to R18 (best verified: 386us steady, 479us harness).
// R19 (latency hoists) was neutral; R20 (replicated E, -1 barrier) regressed
// -3% -- replicated issue cost > barrier saved. Evidence across R18-R20:
// HBM 1%, instrs -30% -> dur -2%, cross-block exchange ~10us/rt (R15).
// The kernel is bound by the 24-step serial recurrence x per-step critical
// path (fenced L2 weight reads -> c -> C -> F -> D -> partials -> E -> x)
// with 3 unavoidable all-to-all barriers/step on 64 CUs. Practical floor.
// ---------------------------------------------------------------------------
__global__ __launch_bounds__(1024, 4) void spat_kernel(
    const float* __restrict__ li,  const float* __restrict__ gi,
    const float* __restrict__ ls,  const float* __restrict__ gs,
    const float* __restrict__ dist,
    const float* __restrict__ la0, const float* __restrict__ ga0,
    const float* __restrict__ Wcl, const float* __restrict__ bcl,
    const float* __restrict__ Wll, const float* __restrict__ bll, const float* __restrict__ vl,
    const float* __restrict__ Wcg, const float* __restrict__ bcg,
    const float* __restrict__ Wlg, const float* __restrict__ blg, const float* __restrict__ vg,
    const float* __restrict__ Wih, const float* __restrict__ bih, const float* __restrict__ bhh,
    float* __restrict__ out)
{
    __shared__ float Eg[6144];               // exp(2*hf_g[o][s]), o<24, s<256
    __shared__ float El[800];                // exp(2*hf_l), idx l*25+o
    __shared__ float outb[6144];             // h outputs  [t][i]
    __shared__ float gasb[6144];             // gas        [t][s]
    __shared__ float lasb[768];              // las        [t][l]
    __shared__ float csb[256];               // c at t=23
    __shared__ float slred[800];             // s_l partials, idx l*25+o
    __shared__ __align__(16) union {
        float wcg[6144];                     // Wcg staging (init only)
        struct {
            float sgred[1024];
            float xv[288];
            float cq[256];
            float slg[32];
        } p;
    } U;
    __shared__ float dstf[256];
    __shared__ float bsum[768];              // bih+bhh: [u]=i, [256+u]=g, [512+u]=o
    __shared__ float bcf[48];                // bll|blg
    __shared__ __align__(16) float4 pl4[12], pg4[12];  // pair coeffs (A0,A1,B1,B2)
    __shared__ float vlf[24], vgf[24], cbuf[2];

    const int b = blockIdx.x, tid = threadIdx.x;
    const int s = tid & 255, ogrp = tid >> 8;

    // ---- small init (before first barrier) ----
    if (tid < 256) dstf[tid] = dist[b*256 + tid];
    if (tid < 24)  { vlf[tid] = vl[tid]; vgf[tid] = vg[tid]; }
    if (tid < 48)  bcf[tid] = (tid < 24) ? bll[tid] : blg[tid - 24];
    if (tid < 768) {
        const int wrow = tid + ((tid >= 256) ? 256 : 0);
        bsum[tid] = bih[wrow] + bhh[wrow];
    }
    if (tid == 0)  { float s1 = 0.f; for (int d = 0; d < 24; d++) s1 += vl[d]; cbuf[0] = s1; }
    if (tid == 1)  { float s1 = 0.f; for (int d = 0; d < 24; d++) s1 += vg[d]; cbuf[1] = s1; }

    // ---- hf_g: thread (s, ogrp) accumulates 6 o's over c<24, j<32 (packed) ----
    v2f acc2[6];
#pragma unroll
    for (int i = 0; i < 6; i++) acc2[i] = (v2f){bcg[ogrp*6 + i], 0.f};

#pragma unroll 1
    for (int hc = 0; hc < 3; hc++) {
        for (int k = tid; k < 6144; k += 1024) {
            const int o = k >> 8, r = k & 255;
            U.wcg[k] = Wcg[o*768 + hc*256 + r];
        }
        __syncthreads();
#pragma unroll 1
        for (int cc = 0; cc < 8; cc++) {
            const int c = hc*8 + cc;
            const v4f* gp = (const v4f*)(gs + ((size_t)b*196608 + c*8192 + s*32));
#pragma unroll
            for (int h = 0; h < 2; h++) {            // two 16-float halves of j
                const v4f g0 = gp[h*4 + 0], g1 = gp[h*4 + 1];
                const v4f g2 = gp[h*4 + 2], g3 = gp[h*4 + 3];
#pragma unroll
                for (int i = 0; i < 6; i++) {
                    const v4f* wp = (const v4f*)(U.wcg + ((ogrp*6 + i)*256 + cc*32)) + h*4;
                    const v4f w0 = wp[0], w1 = wp[1], w2 = wp[2], w3 = wp[3];
                    v2f a = acc2[i];
                    a = PKFMA(w0.xy, g0.xy, a); a = PKFMA(w0.zw, g0.zw, a);
                    a = PKFMA(w1.xy, g1.xy, a); a = PKFMA(w1.zw, g1.zw, a);
                    a = PKFMA(w2.xy, g2.xy, a); a = PKFMA(w2.zw, g2.zw, a);
                    a = PKFMA(w3.xy, g3.xy, a); a = PKFMA(w3.zw, g3.zw, a);
                    acc2[i] = a;
                }
            }
        }
        __syncthreads();
    }
#pragma unroll
    for (int i = 0; i < 6; i++)
        Eg[(ogrp*6 + i)*256 + s] = __expf(2.f*clamp15(acc2[i].x + acc2[i].y));

    // ---- hf_l -> El (transposed: l*25+o) ----
    if (tid < 768) {
        const int o = tid >> 5, l = tid & 31;
        float a = bcl[o];
        for (int c = 0; c < 24; c++)
            a = fmaf(Wcl[o*24 + c], ls[b*768 + c*32 + l], a);
        El[l*25 + o] = __expf(2.f*clamp15(a));
    }

    // ---- x for t=0 (wcg union dead after hc-loop barrier) ----
    if (tid < 288) {
        if (tid < 32) U.p.xv[tid] = la0[b*32 + tid] * li[b*32 + tid];
        else { const int ss = tid - 32; U.p.xv[tid] = ga0[b*256 + ss] * gi[b*256 + ss]; }
    }
    __syncthreads();

    const int u8 = tid & 7, slot = tid >> 3;   // A team layout (128 slots)
    const int u0 = slot*2;                     // slot owns units u0, u0+1

#pragma unroll 1
    for (int t = 0; t < T_; t++) {
        // prefetch next-step inputs for the fused x-build (wave0: li, wave1: gi)
        float liN = 0.f;
        float giN0 = 0.f, giN1 = 0.f, giN2 = 0.f, giN3 = 0.f;
        if (t < T_ - 1) {
            if (tid < 32) liN = li[(t+1)*2048 + b*32 + tid];
            else if (tid >= 64 && tid < 128) {
                const int lane = tid - 64;
                giN0 = gi[(t+1)*16384 + b*256 + lane];
                giN1 = gi[(t+1)*16384 + b*256 + lane + 64];
                giN2 = gi[(t+1)*16384 + b*256 + lane + 128];
                giN3 = gi[(t+1)*16384 + b*256 + lane + 192];
            }
        }

        // ---- A: gates GEMV (i/g/o rows of 2 units per slot), packed,
        //      fused LSTM tail ----
        {
            const v4f* xp = (const v4f*)U.p.xv;
            v2f br0 = {0.f,0.f}, br1 = {0.f,0.f}, br2 = {0.f,0.f};
            v2f br3 = {0.f,0.f}, br4 = {0.f,0.f}, br5 = {0.f,0.f};
#pragma unroll 1
            for (int jc = 0; jc < 3; jc++) {
                const v4f x0 = xp[jc*24 + u8];
                const v4f x1 = xp[jc*24 + 8 + u8];
                const v4f x2 = xp[jc*24 + 16 + u8];

#define KROW(WROW, AR) { \
                const v4f* wp_ = (const v4f*)(Wih + (size_t)(WROW)*288) + jc*24 + u8; \
                const v4f w0_ = wp_[0], w1_ = wp_[8], w2_ = wp_[16]; \
                v2f a_ = AR; \
                a_ = PKFMA(w0_.xy, x0.xy, a_); a_ = PKFMA(w0_.zw, x0.zw, a_); \
                a_ = PKFMA(w1_.xy, x1.xy, a_); a_ = PKFMA(w1_.zw, x1.zw, a_); \
                a_ = PKFMA(w2_.xy, x2.xy, a_); a_ = PKFMA(w2_.zw, x2.zw, a_); \
                AR = a_; }

                KROW(u0,       br0) KROW(512 + u0, br1) KROW(768 + u0, br2)
                __builtin_amdgcn_sched_barrier(0);
                KROW(u0 + 1,   br3) KROW(513 + u0, br4) KROW(769 + u0, br5)
                __builtin_amdgcn_sched_barrier(0);
#undef KROW
            }
            float ar0 = br0.x + br0.y, ar1 = br1.x + br1.y, ar2 = br2.x + br2.y;
            float ar3 = br3.x + br3.y, ar4 = br4.x + br4.y, ar5 = br5.x + br5.y;
            // 8-lane reduce: all lanes end up with the team sums
            ar0 += __shfl_xor(ar0, 1); ar0 += __shfl_xor(ar0, 2); ar0 += __shfl_xor(ar0, 4);
            ar1 += __shfl_xor(ar1, 1); ar1 += __shfl_xor(ar1, 2); ar1 += __shfl_xor(ar1, 4);
            ar2 += __shfl_xor(ar2, 1); ar2 += __shfl_xor(ar2, 2); ar2 += __shfl_xor(ar2, 4);
            ar3 += __shfl_xor(ar3, 1); ar3 += __shfl_xor(ar3, 2); ar3 += __shfl_xor(ar3, 4);
            ar4 += __shfl_xor(ar4, 1); ar4 += __shfl_xor(ar4, 2); ar4 += __shfl_xor(ar4, 4);
            ar5 += __shfl_xor(ar5, 1); ar5 += __shfl_xor(ar5, 2); ar5 += __shfl_xor(ar5, 4);
            if (u8 < 2) {                     // lane0 -> cell u0, lane1 -> cell u0+1
                const int uu = u0 + u8;
                const float ig = (u8 ? ar3 : ar0) + bsum[uu];
                const float gg = (u8 ? ar4 : ar1) + bsum[256 + uu];
                const float ot = (u8 ? ar5 : ar2) + bsum[512 + uu];
                const float sig_i = rcp_(1.f + __expf(-ig));
                const float th_g  = 1.f - 2.f*rcp_(1.f + __expf(2.f*clamp15(gg)));
                const float c     = sig_i * th_g;
                const float sig_o = rcp_(1.f + __expf(-ot));
                const float th_c  = 1.f - 2.f*rcp_(1.f + __expf(2.f*c));
                const float h     = sig_o * th_c;
                U.p.cq[uu] = c;
                outb[t*256 + uu] = h;
                if (t == T_ - 1) csb[uu] = c;
            }
        }
        __syncthreads();                              // #1: cq/outb ready

        // ---- C: 48 dots x 16-lane teams (packed); F = exp(2y); pair coeffs ----
        if (tid < 768) {
            const int dot = tid >> 4, l16 = tid & 15;
            const float* Wr = (dot < 24) ? (Wll + dot*256) : (Wlg + (dot - 24)*256);
            const v4f* wp = (const v4f*)Wr + l16*4;
            const v4f* cp = (const v4f*)U.p.cq + l16*4;
            v2f a2 = {0.f, 0.f};
#pragma unroll
            for (int m = 0; m < 4; m++) {
                const v4f w0 = wp[m], c0 = cp[m];
                a2 = PKFMA(w0.xy, c0.xy, a2);
                a2 = PKFMA(w0.zw, c0.zw, a2);
            }
            float a = a2.x + a2.y;
            a += __shfl_xor(a, 1); a += __shfl_xor(a, 2);
            a += __shfl_xor(a, 4); a += __shfl_xor(a, 8);
            const float F  = __expf(2.f*clamp15(a + bcf[dot]));
            const float v  = (dot < 24) ? vlf[dot] : vgf[dot - 24];
            const float Fo = __shfl_xor(F, 16);        // partner team (dot^1)
            const float vo = (dot < 24) ? vlf[dot ^ 1] : vgf[(dot ^ 1) - 24];
            if ((tid & 31) == 0) {                     // lane 0 of even dot
                const float A0 = v + vo;
                const float A1 = fmaf(v, Fo, vo * F);
                const float B1 = F + Fo;
                const float B2 = F * Fo;
                const int P2 = dot >> 1;               // 0..23
                if (P2 < 12) pl4[P2]      = make_float4(A0, A1, B1, B2);
                else         pg4[P2 - 12] = make_float4(A0, A1, B1, B2);
            }
        }
        __syncthreads();                              // #2

        // ---- D: s_g partials (all threads, packed v_pk_fma over o-pairs)
        //      + s_l partials (tid<768, scalar) ----
        {
            float z[6];
#pragma unroll
            for (int i = 0; i < 6; i++) z[i] = Eg[(ogrp*6 + i)*256 + s];
            const v2f zv0 = {z[0], z[1]}, zv1 = {z[2], z[3]}, zv2 = {z[4], z[5]};
            const v2f z2v0 = zv0*zv0, z2v1 = zv1*zv1, z2v2 = zv2*zv2;
            const v2f one2 = {1.f, 1.f};
            v2f acc2d = {0.f, 0.f};
#pragma unroll 4
            for (int p = 0; p < 12; p++) {
                const float4 q = pg4[p];
                const v2f qx = {q.x, q.x}, qy = {q.y, q.y};
                const v2f qz = {q.z, q.z}, qw = {q.w, q.w};
                const v2f n0 = PKFMA(zv0, qy, qx);
                const v2f n1 = PKFMA(zv1, qy, qx);
                const v2f n2 = PKFMA(zv2, qy, qx);
                const v2f d0 = PKFMA(z2v0, qw, PKFMA(zv0, qz, one2));
                const v2f d1 = PKFMA(z2v1, qw, PKFMA(zv1, qz, one2));
                const v2f d2 = PKFMA(z2v2, qw, PKFMA(zv2, qz, one2));
                const v2f r0 = {rcp_(d0.x), rcp_(d0.y)};
                const v2f r1 = {rcp_(d1.x), rcp_(d1.y)};
                const v2f r2 = {rcp_(d2.x), rcp_(d2.y)};
                acc2d = PKFMA(n0, r0, acc2d);
                acc2d = PKFMA(n1, r1, acc2d);
                acc2d = PKFMA(n2, r2, acc2d);
            }
            U.p.sgred[tid] = acc2d.x + acc2d.y;
        }
        if (tid < 768) {
            const int l = tid / 24, o = tid - l*24;
            const float E  = El[l*25 + o];
            const float E2 = E*E;
            float b0 = 0.f, b1 = 0.f;
#pragma unroll 4
            for (int p = 0; p < 12; p += 2) {
                const float4 q0 = pl4[p], q1 = pl4[p+1];
                const float n0 = fmaf(E, q0.y, q0.x);
                const float d0 = fmaf(E2, q0.w, fmaf(E, q0.z, 1.f));
                const float n1 = fmaf(E, q1.y, q1.x);
                const float d1 = fmaf(E2, q1.w, fmaf(E, q1.z, 1.f));
                b0 = fmaf(n0, rcp_(d0), b0);
                b1 = fmaf(n1, rcp_(d1), b1);
            }
            slred[l*25 + o] = b0 + b1;
        }
        __syncthreads();                              // #3

        // ---- E: both softmaxes + next-step x-build (LDS outputs) ----
        if (tid < 32) {                       // wave0: s_l softmax
            float tot = 0.f;
#pragma unroll
            for (int o2 = 0; o2 < 24; o2++) tot += slred[tid*25 + o2];
            const float sv = 24.f*cbuf[0] - 2.f*tot;
            float m = sv;
#pragma unroll
            for (int mk = 16; mk >= 1; mk >>= 1) m = fmaxf(m, __shfl_xor(m, mk));
            const float e = __expf(sv - m);
            float ss = e;
#pragma unroll
            for (int mk = 16; mk >= 1; mk >>= 1) ss += __shfl_xor(ss, mk);
            const float r = e * rcp_(ss);
            lasb[t*32 + tid] = r;
            if (t < T_ - 1) U.p.xv[tid] = r * liN;
        } else if (tid >= 64 && tid < 128) {  // wave1: s_g softmax, 4 s/lane
            const int lane = tid - 64;
            float vv0, vv1, vv2, vv3;
            {
                const float t0 = U.p.sgred[lane]     + U.p.sgred[256+lane]     + U.p.sgred[512+lane]     + U.p.sgred[768+lane];
                const float t1 = U.p.sgred[lane+64]  + U.p.sgred[256+lane+64]  + U.p.sgred[512+lane+64]  + U.p.sgred[768+lane+64];
                const float t2 = U.p.sgred[lane+128] + U.p.sgred[256+lane+128] + U.p.sgred[512+lane+128] + U.p.sgred[768+lane+128];
                const float t3 = U.p.sgred[lane+192] + U.p.sgred[256+lane+192] + U.p.sgred[512+lane+192] + U.p.sgred[768+lane+192];
                vv0 = (1.f-LAMDA_)*(24.f*cbuf[1] - 2.f*t0) + LAMDA_*dstf[lane];
                vv1 = (1.f-LAMDA_)*(24.f*cbuf[1] - 2.f*t1) + LAMDA_*dstf[lane+64];
                vv2 = (1.f-LAMDA_)*(24.f*cbuf[1] - 2.f*t2) + LAMDA_*dstf[lane+128];
                vv3 = (1.f-LAMDA_)*(24.f*cbuf[1] - 2.f*t3) + LAMDA_*dstf[lane+192];
            }
            float m = fmaxf(fmaxf(vv0, vv1), fmaxf(vv2, vv3));
#pragma unroll
            for (int mk = 32; mk >= 1; mk >>= 1) m = fmaxf(m, __shfl_xor(m, mk));
            const float e0 = __expf(vv0 - m), e1 = __expf(vv1 - m);
            const float e2 = __expf(vv2 - m), e3 = __expf(vv3 - m);
            float ss = (e0 + e1) + (e2 + e3);
#pragma unroll
            for (int mk = 32; mk >= 1; mk >>= 1) ss += __shfl_xor(ss, mk);
            const float inv = rcp_(ss);
            const float r0 = e0*inv, r1 = e1*inv, r2 = e2*inv, r3 = e3*inv;
            float* gb = gasb + t*256;
            gb[lane] = r0; gb[lane+64] = r1; gb[lane+128] = r2; gb[lane+192] = r3;
            if (t < T_ - 1) {
                U.p.xv[32+lane]     = r0 * giN0;
                U.p.xv[32+lane+64]  = r1 * giN1;
                U.p.xv[32+lane+128] = r2 * giN2;
                U.p.xv[32+lane+192] = r3 * giN3;
            }
        }
        __syncthreads();                              // #4
    }

    // ---- final flush: LDS output buffers -> global, coalesced ----
    for (int k = tid; k < 6144; k += 1024) {
        const int tt = k >> 8, ii = k & 255;
        out[tt*16384 + b*256 + ii]           = outb[k];
        out[OFF_GAS + tt*16384 + b*256 + ii] = gasb[k];
    }
    if (tid < 768) out[OFF_LAS + (tid >> 5)*2048 + b*32 + (tid & 31)] = lasb[tid];
    if (tid < 256) out[OFF_CS + b*256 + tid] = csb[tid];
}

extern "C" void kernel_launch(void* const* d_in, const int* in_sizes, int n_in,
                              void* d_out, int out_size, void* d_ws, size_t ws_size,
                              hipStream_t stream)
{
    const float* li   = (const float*)d_in[0];
    const float* gi   = (const float*)d_in[1];
    const float* ls   = (const float*)d_in[2];
    const float* gs   = (const float*)d_in[3];
    const float* dist = (const float*)d_in[4];
    const float* la0  = (const float*)d_in[5];
    const float* ga0  = (const float*)d_in[6];
    const float* Wcl  = (const float*)d_in[7];
    const float* bcl  = (const float*)d_in[8];
    const float* Wll  = (const float*)d_in[9];
    const float* bll  = (const float*)d_in[10];
    const float* vl   = (const float*)d_in[11];
    const float* Wcg  = (const float*)d_in[12];
    const float* bcg  = (const float*)d_in[13];
    const float* Wlg  = (const float*)d_in[14];
    const float* blg  = (const float*)d_in[15];
    const float* vg   = (const float*)d_in[16];
    const float* Wih  = (const float*)d_in[17];
    const float* bih  = (const float*)d_in[18];
    const float* bhh  = (const float*)d_in[19];

    spat_kernel<<<64, 1024, 0, stream>>>(li, gi, ls, gs, dist, la0, ga0,
                                         Wcl, bcl, Wll, bll, vl,
                                         Wcg, bcg, Wlg, blg, vg,
                                         Wih, bih, bhh, (float*)d_out);
}